// Round 1
// baseline (138.078 us; speedup 1.0000x reference)
//
#include <hip/hip_runtime.h>

// SparsePropMaxPool closed form:
//   ori_map_h[b,h,s,e] = max(x[b,h,s..e]) if (s, d=e-s) in SET else 0
//   SET: d in [0,15] any s  |  d odd in [17,31], s even  |  d%4==3 in [35,63], s%4==0
//   props_h[b,p,h] = max(x[b,h, s_p .. s_p+d_p])   (constant (s_p,d_p) table, 153 entries)
//   mask[b,0,s,e] = 1 at SET positions
// Output layout (flat, return order): props_h (64*153*512) | ori_map_h (64*512*64*64) | mask (64*64*64)

#define B_ 64
#define H_ 512
#define N_ 64
#define NPROP 153

__device__ __forceinline__ bool in_set(int s, int d) {
    if (d < 0) return false;
    if (d <= 15) return true;
    if (d <= 31) return (d & 1) && ((s & 1) == 0);       // 17,19,...,31 odd; s even
    return ((d & 3) == 3) && ((s & 3) == 0);             // 35,39,...,63; s % 4 == 0
}

__device__ __forceinline__ void decode_prop(int p, int& s, int& d) {
    if (p < 57)       { s = p;           d = 7;  }
    else if (p < 106) { s = p - 57;      d = 15; }
    else if (p < 127) { s = 2*(p - 106); d = 23; }
    else if (p < 144) { s = 2*(p - 127); d = 31; }
    else if (p < 149) { s = 4*(p - 144); d = 47; }
    else if (p < 152) { s = 4*(p - 149); d = 55; }
    else              { s = 0;           d = 63; }
}

__global__ __launch_bounds__(64) void sparse_prop_kernel(
        const float* __restrict__ x,
        float* __restrict__ out_props,
        float* __restrict__ out_map,
        float* __restrict__ out_mask) {
    const int bh   = blockIdx.x;        // b*512 + h
    const int b    = bh >> 9;
    const int h    = bh & (H_ - 1);
    const int lane = threadIdx.x;       // 0..63 == e index

    __shared__ float xs[N_];
    xs[lane] = x[(size_t)bh * N_ + lane];
    __syncthreads();

    // Map: iterate s from 63 down to 0; v holds max(x[s..lane]) for lane >= s.
    float* mrow = out_map + (size_t)bh * (N_ * N_);
    float v = 0.0f;
    #pragma unroll
    for (int s = N_ - 1; s >= 0; --s) {
        float xsv = xs[s];
        v = (lane == s) ? xsv : fmaxf(v, xsv);   // lanes < s hold garbage; masked to 0 below
        int d = lane - s;
        mrow[s * N_ + lane] = in_set(s, d) ? v : 0.0f;   // coalesced 256B row store
    }

    // props_h[b,p,h]: direct range-max from LDS (3 rounds: d<=15, d<=31, d<=63)
    for (int p = lane; p < NPROP; p += 64) {
        int s, d; decode_prop(p, s, d);
        float m = xs[s];
        for (int j = 1; j <= d; ++j) m = fmaxf(m, xs[s + j]);
        out_props[((size_t)b * NPROP + p) * H_ + h] = m;
    }

    // mask (identical content per b): written by the h==0 block of each b
    if (h == 0) {
        float* mk = out_mask + (size_t)b * (N_ * N_);
        #pragma unroll
        for (int s = 0; s < N_; ++s)
            mk[s * N_ + lane] = in_set(s, lane - s) ? 1.0f : 0.0f;
    }
}

extern "C" void kernel_launch(void* const* d_in, const int* in_sizes, int n_in,
                              void* d_out, int out_size, void* d_ws, size_t ws_size,
                              hipStream_t stream) {
    const float* x = (const float*)d_in[0];   // (64, 512, 64) f32
    float* out       = (float*)d_out;
    float* out_props = out;                                   // 64*153*512   = 5,013,504
    float* out_map   = out + (size_t)B_ * NPROP * H_;         // 64*512*64*64 = 134,217,728
    float* out_mask  = out_map + (size_t)B_ * H_ * N_ * N_;   // 64*64*64     = 262,144

    sparse_prop_kernel<<<dim3(B_ * H_), dim3(64), 0, stream>>>(x, out_props, out_map, out_mask);
}

// Round 2
// 110.862 us; speedup vs baseline: 1.2455x; 1.2455x over previous
//
#include <hip/hip_runtime.h>

// SparsePropMaxPool closed form (verified round 1, absmax=0):
//   ori_map_h[b,h,s,e] = max(x[b,h,s..e]) if (s, d=e-s) in SET else 0
//   SET: d in [0,15] any s | d odd in [17,31], s even | d%4==3 in [35,63], s%4==0
//   props_h[b,p,h] = max(x[b,h, s_p .. s_p+d_p])  (153 constant ranges)
//   mask[b,0,s,e] = 1 at SET positions
// Out layout: props (64*153*512) | map (64*512*64*64) | mask (64*64*64)

#define B_ 64
#define H_ 512
#define N_ 64
#define NPROP 153

__device__ __forceinline__ bool in_set(int s, int d) {
    if (d < 0) return false;
    if (d <= 15) return true;
    if (d <= 31) return (d & 1) && ((s & 1) == 0);        // d=17,19..31 odd, s even
    return (d >= 35) && ((d & 3) == 3) && ((s & 3) == 0); // d=35,39..63, s%4==0
}

// ---------------- map kernel: 8 bh-rows per 128-thread block, float4 stores ----
__global__ __launch_bounds__(128) void map_kernel(const float* __restrict__ x,
                                                  float* __restrict__ out_map) {
    const int lane = threadIdx.x;       // 0..127
    const int g    = lane >> 4;         // row within block 0..7
    const int t    = lane & 15;         // float4 column 0..15
    const size_t bh = (size_t)blockIdx.x * 8 + g;

    // [8][72] float: row base 288B (16B-aligned), banks (8g+4t)%32 -> 2-way max (free)
    __shared__ __align__(16) float xs[8][72];
    float4 xv = reinterpret_cast<const float4*>(x)[blockIdx.x * 128 + lane];
    *reinterpret_cast<float4*>(&xs[g][4 * t]) = xv;
    __syncthreads();

    float4* mrow = reinterpret_cast<float4*>(out_map + bh * (size_t)(N_ * N_));
    const int e0 = 4 * t;
    float vx = 0.f, vy = 0.f, vz = 0.f, vw = 0.f;
    #pragma unroll
    for (int s = N_ - 1; s >= 0; --s) {   // v_j = max(x[s..e_j]), reset at s==e_j
        const float m = xs[g][s];          // 4-address broadcast, conflict-free
        vx = (s == e0 + 0) ? m : fmaxf(vx, m);
        vy = (s == e0 + 1) ? m : fmaxf(vy, m);
        vz = (s == e0 + 2) ? m : fmaxf(vz, m);
        vw = (s == e0 + 3) ? m : fmaxf(vw, m);
        float4 w;
        w.x = in_set(s, e0 + 0 - s) ? vx : 0.f;   // s,j compile-time: folds to t-compares
        w.y = in_set(s, e0 + 1 - s) ? vy : 0.f;
        w.z = in_set(s, e0 + 2 - s) ? vz : 0.f;
        w.w = in_set(s, e0 + 3 - s) ? vw : 0.f;
        mrow[s * 16 + t] = w;              // 16B/lane, 4x256B chunks per wave
    }
}

// ---------------- props+mask kernel: lane = h, contiguous 256B stores ----------
// All 153 ranges are unions of 8-aligned length-8 windows -> T3[i]=max(x[i..i+7])
// answers everything. T3 built per-lane in registers (fully unrolled, static idx).
__global__ __launch_bounds__(64) void props_kernel(const float* __restrict__ x,
                                                   float* __restrict__ out_props,
                                                   float* __restrict__ out_mask) {
    const int lane = threadIdx.x;            // h within 64-chunk
    const int b = blockIdx.x >> 3;
    const int c = blockIdx.x & 7;
    const int h = c * 64 + lane;

    const float4* xr = reinterpret_cast<const float4*>(x + ((size_t)b * H_ + h) * N_);
    float r[64];
    #pragma unroll
    for (int k = 0; k < 16; ++k) {
        float4 v = xr[k];
        r[4*k+0] = v.x; r[4*k+1] = v.y; r[4*k+2] = v.z; r[4*k+3] = v.w;
    }
    float a[63];
    #pragma unroll
    for (int i = 0; i < 63; ++i) a[i] = fmaxf(r[i], r[i+1]);
    float bb[61];
    #pragma unroll
    for (int i = 0; i < 61; ++i) bb[i] = fmaxf(a[i], a[i+2]);
    float T3[57];
    #pragma unroll
    for (int i = 0; i < 57; ++i) T3[i] = fmaxf(bb[i], bb[i+4]);

    float* po = out_props + (size_t)b * NPROP * H_ + h;
    int p = 0;
    #pragma unroll
    for (int s = 0; s < 57; ++s)              // d=7
        po[(size_t)(p++) * H_] = T3[s];
    #pragma unroll
    for (int s = 0; s < 49; ++s)              // d=15
        po[(size_t)(p++) * H_] = fmaxf(T3[s], T3[s + 8]);
    #pragma unroll
    for (int s = 0; s <= 40; s += 2)          // d=23
        po[(size_t)(p++) * H_] = fmaxf(fmaxf(T3[s], T3[s + 8]), T3[s + 16]);
    #pragma unroll
    for (int s = 0; s <= 32; s += 2)          // d=31
        po[(size_t)(p++) * H_] =
            fmaxf(fmaxf(T3[s], T3[s + 8]), fmaxf(T3[s + 16], T3[s + 24]));
    #pragma unroll
    for (int s = 0; s <= 16; s += 4) {        // d=47 (6 windows)
        float m = T3[s];
        #pragma unroll
        for (int j = 8; j <= 40; j += 8) m = fmaxf(m, T3[s + j]);
        po[(size_t)(p++) * H_] = m;
    }
    #pragma unroll
    for (int s = 0; s <= 8; s += 4) {         // d=55 (7 windows)
        float m = T3[s];
        #pragma unroll
        for (int j = 8; j <= 48; j += 8) m = fmaxf(m, T3[s + j]);
        po[(size_t)(p++) * H_] = m;
    }
    {                                         // d=63, s=0 (8 windows)
        float m = T3[0];
        #pragma unroll
        for (int j = 8; j <= 56; j += 8) m = fmaxf(m, T3[j]);
        po[(size_t)p * H_] = m;
    }

    if (c == 0) {                             // mask: per-b content, h==chunk0 writes
        float* mk = out_mask + (size_t)b * (N_ * N_);
        #pragma unroll
        for (int s = 0; s < N_; ++s)
            mk[s * N_ + lane] = in_set(s, lane - s) ? 1.0f : 0.0f;
    }
}

extern "C" void kernel_launch(void* const* d_in, const int* in_sizes, int n_in,
                              void* d_out, int out_size, void* d_ws, size_t ws_size,
                              hipStream_t stream) {
    const float* x = (const float*)d_in[0];   // (64, 512, 64) f32
    float* out       = (float*)d_out;
    float* out_props = out;                                   // 5,013,504
    float* out_map   = out + (size_t)B_ * NPROP * H_;         // 134,217,728
    float* out_mask  = out_map + (size_t)B_ * H_ * N_ * N_;   // 262,144

    props_kernel<<<dim3(B_ * (H_ / 64)), dim3(64), 0, stream>>>(x, out_props, out_mask);
    map_kernel<<<dim3(B_ * H_ / 8), dim3(128), 0, stream>>>(x, out_map);
}